// Round 6
// baseline (190.290 us; speedup 1.0000x reference)
//
#include <hip/hip_runtime.h>
#include <hip/hip_bf16.h>

#define NSPLIT 8
#define BIGF 1e30f
#define MARGIN 0.3f
#define DK 128
#define LDA 136   // padded LDS stride (bf16 elems)

typedef __attribute__((ext_vector_type(8))) short bf16x8;
typedef __attribute__((ext_vector_type(4))) float f32x4;

// workspace word offsets
#define WS_HP   0                  // 8192 u32 keys: max d2_pos (order-preserving map)
#define WS_HN   8192               // 8192 u32 keys: ~key(d2_neg) => min via complement
#define WS_BCNT 16384              // u32 completion counter
#define WS_SQ   16388              // 8192 f32 squared norms
#define WS_XB   24580              // bf16 X copy (16B aligned)

// Order-preserving float->uint key; sentinels (+/-BIGF +/- sq) survive the
// atomic max merge and encode validity exactly. Init 0 < every real key.
__device__ __forceinline__ unsigned encf(float f) {
    unsigned u = __float_as_uint(f);
    return (u & 0x80000000u) ? ~u : (u | 0x80000000u);
}
__device__ __forceinline__ float decf(unsigned k) {
    return (k & 0x80000000u) ? __uint_as_float(k & 0x7FFFFFFFu)
                             : __uint_as_float(~k);
}

// Kernel 1: bf16 copy of X + exact fp32 squared norms + ws init.
__global__ void prep_kernel(const float* __restrict__ x, ushort* __restrict__ xb,
                            float* __restrict__ sq, unsigned* __restrict__ hp,
                            unsigned* __restrict__ hn, unsigned* __restrict__ bcnt,
                            int N) {
    if (blockIdx.x == 0 && threadIdx.x == 0) *bcnt = 0u;
    int wave = threadIdx.x >> 6;
    int lane = threadIdx.x & 63;
    int row = blockIdx.x * 4 + wave;
    if (row >= N) return;
    const float2* xr = (const float2*)(x + (size_t)row * DK);
    float2 v = xr[lane];
    __hip_bfloat16 b0 = __float2bfloat16(v.x);
    __hip_bfloat16 b1 = __float2bfloat16(v.y);
    ushort2 st;
    st.x = *(ushort*)&b0;
    st.y = *(ushort*)&b1;
    ((ushort2*)(xb + (size_t)row * DK))[lane] = st;
    float s = v.x * v.x + v.y * v.y;
    #pragma unroll
    for (int o = 32; o > 0; o >>= 1) s += __shfl_xor(s, o, 64);
    if (lane == 0) {
        sq[row] = s;
        hp[row] = 0u;
        hn[row] = 0u;
    }
}

// Kernel 2: fused bf16-MFMA dist^2 + masked max/min in t = sqb - 2*dot domain.
// Block = 4 waves, 64x64 tile; wave = 32x32 sub-tile (wrow=(w>>1)*32, wcol=(w&1)*32).
// Small wave tile keeps live VGPR ~110 -> 4 waves/SIMD (rounds 3/5 showed >130 spills).
// Grid (N/64, NSPLIT) = 1024 blocks = 4/CU resident.
__global__ __launch_bounds__(256, 2) void tile_kernel(
    const ushort* __restrict__ xb, const float* __restrict__ sq,
    const int* __restrict__ lab,
    unsigned* __restrict__ hp_bits, unsigned* __restrict__ hn_bits,
    unsigned* __restrict__ bcnt, float* __restrict__ out, int N)
{
    __shared__ ushort a_s[64 * LDA];
    __shared__ int   laba_s[64];
    __shared__ float red_hp[64][2];
    __shared__ float red_hn[64][2];
    __shared__ float s_sum[256];
    __shared__ float s_cnt[256];
    __shared__ bool  s_last;

    const int tid  = threadIdx.x;
    const int lane = tid & 63;
    const int wave = tid >> 6;
    const int m16  = lane & 15;
    const int quad = lane >> 4;
    const int rbase = blockIdx.x * 64;
    const int wrow = (wave >> 1) * 32;
    const int wcol = (wave & 1) * 32;

    // Stage A tile (64x128 bf16) into padded LDS.
    for (int c = tid; c < 64 * 16; c += 256) {
        int r = c >> 4, c8 = c & 15;
        *(bf16x8*)(a_s + r * LDA + c8 * 8) =
            *(const bf16x8*)(xb + (size_t)(rbase + r) * DK + c8 * 8);
    }
    if (tid < 64) laba_s[tid] = lab[rbase + tid];
    __syncthreads();

    int rlab[2][4];
    #pragma unroll
    for (int mt = 0; mt < 2; ++mt)
        #pragma unroll
        for (int r = 0; r < 4; ++r)
            rlab[mt][r] = laba_s[wrow + mt * 16 + quad * 4 + r];

    float runhp[2][4], runhn[2][4];
    #pragma unroll
    for (int mt = 0; mt < 2; ++mt)
        #pragma unroll
        for (int r = 0; r < 4; ++r) { runhp[mt][r] = -BIGF; runhn[mt][r] = BIGF; }

    const int cps = N / NSPLIT;                 // 1024
    const int cbegin = blockIdx.y * cps;

    for (int ci = 0; ci < cps; ci += 64) {
        const int cbase = cbegin + ci;

        float sqbv[2]; int lbv[2];
        #pragma unroll
        for (int nt = 0; nt < 2; ++nt) {
            int colg = cbase + wcol + nt * 16 + m16;
            sqbv[nt] = sq[colg];
            lbv[nt]  = lab[colg];
        }

        f32x4 acc[2][2];
        #pragma unroll
        for (int mt = 0; mt < 2; ++mt)
            #pragma unroll
            for (int nt = 0; nt < 2; ++nt)
                acc[mt][nt] = (f32x4){0.f, 0.f, 0.f, 0.f};

        #pragma unroll
        for (int s = 0; s < 4; ++s) {
            bf16x8 bfr[2], afr[2];
            #pragma unroll
            for (int nt = 0; nt < 2; ++nt)
                bfr[nt] = *(const bf16x8*)(xb + (size_t)(cbase + wcol + nt * 16 + m16) * DK
                                           + s * 32 + quad * 8);
            #pragma unroll
            for (int mt = 0; mt < 2; ++mt)
                afr[mt] = *(const bf16x8*)(a_s + (wrow + mt * 16 + m16) * LDA
                                           + s * 32 + quad * 8);
            #pragma unroll
            for (int mt = 0; mt < 2; ++mt)
                #pragma unroll
                for (int nt = 0; nt < 2; ++nt)
                    acc[mt][nt] = __builtin_amdgcn_mfma_f32_16x16x32_bf16(
                        afr[mt], bfr[nt], acc[mt][nt], 0, 0, 0);
        }

        if (cbase == rbase) {
            // diagonal tile (wave-uniform branch): exclude self-pairs from hp
            #pragma unroll
            for (int nt = 0; nt < 2; ++nt) {
                int colg = cbase + wcol + nt * 16 + m16;
                #pragma unroll
                for (int mt = 0; mt < 2; ++mt)
                    #pragma unroll
                    for (int r = 0; r < 4; ++r) {
                        float t = fmaf(-2.0f, acc[mt][nt][r], sqbv[nt]);
                        int rowg = rbase + wrow + mt * 16 + quad * 4 + r;
                        bool same = (rlab[mt][r] == lbv[nt]);
                        bool pos = same && (rowg != colg);
                        runhp[mt][r] = fmaxf(runhp[mt][r], pos ? t : -BIGF);
                        runhn[mt][r] = fminf(runhn[mt][r], same ? BIGF : t);
                    }
            }
        } else {
            #pragma unroll
            for (int nt = 0; nt < 2; ++nt) {
                #pragma unroll
                for (int mt = 0; mt < 2; ++mt)
                    #pragma unroll
                    for (int r = 0; r < 4; ++r) {
                        float t = fmaf(-2.0f, acc[mt][nt][r], sqbv[nt]);
                        bool same = (rlab[mt][r] == lbv[nt]);
                        runhp[mt][r] = fmaxf(runhp[mt][r], same ? t : -BIGF);
                        runhn[mt][r] = fminf(runhn[mt][r], same ? BIGF : t);
                    }
            }
        }
    }

    // reduce across the 16 m16-lanes sharing each row
    #pragma unroll
    for (int mt = 0; mt < 2; ++mt)
        #pragma unroll
        for (int r = 0; r < 4; ++r) {
            #pragma unroll
            for (int o = 8; o > 0; o >>= 1) {
                runhp[mt][r] = fmaxf(runhp[mt][r], __shfl_xor(runhp[mt][r], o, 16));
                runhn[mt][r] = fminf(runhn[mt][r], __shfl_xor(runhn[mt][r], o, 16));
            }
        }

    if (m16 == 0) {
        #pragma unroll
        for (int mt = 0; mt < 2; ++mt)
            #pragma unroll
            for (int r = 0; r < 4; ++r) {
                int rowl = wrow + mt * 16 + quad * 4 + r;
                red_hp[rowl][wave & 1] = runhp[mt][r];
                red_hn[rowl][wave & 1] = runhn[mt][r];
            }
    }
    __syncthreads();
    if (tid < 64) {
        float thp = fmaxf(red_hp[tid][0], red_hp[tid][1]);
        float thn = fminf(red_hn[tid][0], red_hn[tid][1]);
        float sqa = sq[rbase + tid];
        atomicMax(&hp_bits[rbase + tid], encf(sqa + thp));
        atomicMax(&hn_bits[rbase + tid], ~encf(sqa + thn));
    }

    // ---- last block does the finalize (saves a dispatch) ----
    __syncthreads();
    __threadfence();
    if (tid == 0) {
        unsigned tot = gridDim.x * gridDim.y;
        unsigned o = atomicAdd(bcnt, 1u);
        s_last = (o == tot - 1);
    }
    __syncthreads();
    if (!s_last) return;

    float lsum = 0.0f, lcnt = 0.0f;
    for (int base = 0; base < N; base += 256 * 8) {
        unsigned kp[8], kn[8];
        #pragma unroll
        for (int j = 0; j < 8; ++j) {
            int r = base + j * 256 + tid;
            kp[j] = (r < N) ? __hip_atomic_load(&hp_bits[r], __ATOMIC_RELAXED,
                                                __HIP_MEMORY_SCOPE_AGENT) : 0u;
            kn[j] = (r < N) ? __hip_atomic_load(&hn_bits[r], __ATOMIC_RELAXED,
                                                __HIP_MEMORY_SCOPE_AGENT) : 0u;
        }
        #pragma unroll
        for (int j = 0; j < 8; ++j) {
            int r = base + j * 256 + tid;
            if (r >= N) continue;
            float hpv = decf(kp[j]);
            float hnv = decf(~kn[j]);
            if (hpv > -0.5f * BIGF && hnv < 0.5f * BIGF) {
                float dp = sqrtf(fmaxf(hpv, 0.0f));
                float dn = sqrtf(fmaxf(hnv, 0.0f));
                lsum += fmaxf(dp - dn + MARGIN, 0.0f);
                lcnt += 1.0f;
            }
        }
    }
    s_sum[tid] = lsum; s_cnt[tid] = lcnt;
    __syncthreads();
    for (int o = 128; o > 0; o >>= 1) {
        if (tid < o) { s_sum[tid] += s_sum[tid + o]; s_cnt[tid] += s_cnt[tid + o]; }
        __syncthreads();
    }
    if (tid == 0) out[0] = (s_cnt[0] > 0.0f) ? s_sum[0] / s_cnt[0] : 0.0f;
}

extern "C" void kernel_launch(void* const* d_in, const int* in_sizes, int n_in,
                              void* d_out, int out_size, void* d_ws, size_t ws_size,
                              hipStream_t stream) {
    const float* x = (const float*)d_in[0];
    const int* lab = (const int*)d_in[1];
    float* out = (float*)d_out;
    const int N = in_sizes[1];          // 8192

    unsigned* ws = (unsigned*)d_ws;
    unsigned* hp_bits = ws + WS_HP;
    unsigned* hn_bits = ws + WS_HN;
    unsigned* bcnt    = ws + WS_BCNT;
    float* sq  = (float*)(ws + WS_SQ);
    ushort* xb = (ushort*)(ws + WS_XB);

    prep_kernel<<<N / 4, 256, 0, stream>>>(x, xb, sq, hp_bits, hn_bits, bcnt, N);
    dim3 grid(N / 64, NSPLIT);
    tile_kernel<<<grid, 256, 0, stream>>>(xb, sq, lab, hp_bits, hn_bits, bcnt, out, N);
}

// Round 7
// 152.017 us; speedup vs baseline: 1.2518x; 1.2518x over previous
//
#include <hip/hip_runtime.h>
#include <hip/hip_bf16.h>

#define NSPLIT 16
#define BIGF 1e30f
#define MARGIN 0.3f
#define DK 128            // row length (bf16 elems) = 256 B = 16 chunks of 16 B

typedef __attribute__((ext_vector_type(8))) short bf16x8;
typedef __attribute__((ext_vector_type(4))) float f32x4;

// workspace word offsets
#define WS_HP   0                  // 8192 u32 keys: max d2_pos (order-preserving map)
#define WS_HN   8192               // 8192 u32 keys: ~key(d2_neg) => min via complement
#define WS_BCNT 16384              // u32 completion counter
#define WS_SQ   16388              // 8192 f32 squared norms
#define WS_XB   24580              // bf16 X copy (16B aligned)

typedef __attribute__((address_space(1))) const void gas_t;
typedef __attribute__((address_space(3))) void las_t;

// Order-preserving float->uint key; +/-BIGF sentinels survive the atomic-max
// merge and encode validity exactly. Init 0 < every real key.
__device__ __forceinline__ unsigned encf(float f) {
    unsigned u = __float_as_uint(f);
    return (u & 0x80000000u) ? ~u : (u | 0x80000000u);
}
__device__ __forceinline__ float decf(unsigned k) {
    return (k & 0x80000000u) ? __uint_as_float(k & 0x7FFFFFFFu)
                             : __uint_as_float(~k);
}

// Kernel 1: bf16 copy of X + exact fp32 squared norms + ws init.
__global__ void prep_kernel(const float* __restrict__ x, ushort* __restrict__ xb,
                            float* __restrict__ sq, unsigned* __restrict__ hp,
                            unsigned* __restrict__ hn, unsigned* __restrict__ bcnt,
                            int N) {
    if (blockIdx.x == 0 && threadIdx.x == 0) *bcnt = 0u;
    int wave = threadIdx.x >> 6;
    int lane = threadIdx.x & 63;
    int row = blockIdx.x * 4 + wave;
    if (row >= N) return;
    const float2* xr = (const float2*)(x + (size_t)row * DK);
    float2 v = xr[lane];
    __hip_bfloat16 b0 = __float2bfloat16(v.x);
    __hip_bfloat16 b1 = __float2bfloat16(v.y);
    ushort2 st;
    st.x = *(ushort*)&b0;
    st.y = *(ushort*)&b1;
    ((ushort2*)(xb + (size_t)row * DK))[lane] = st;
    float s = v.x * v.x + v.y * v.y;
    #pragma unroll
    for (int o = 32; o > 0; o >>= 1) s += __shfl_xor(s, o, 64);
    if (lane == 0) {
        sq[row] = s;
        hp[row] = 0u;
        hn[row] = 0u;
    }
}

// Stage 32 rows (256 B each) of xb into a swizzled LDS tile via global_load_lds.
// LDS slot s of row holds global chunk (s ^ (row&15)); global side is a
// permuted gather within each 256 B row (coalescing preserved), LDS side is
// the mandatory wave-uniform base + lane*16.
__device__ __forceinline__ void stage32(const ushort* __restrict__ src_base,
                                        ushort* lds_base, int r0,
                                        int lane) {
    int rsub = lane >> 4;          // 0..3
    int slot = lane & 15;          // 0..15
    #pragma unroll
    for (int j = 0; j < 8; ++j) {
        int row = r0 + j * 4 + rsub;
        const ushort* g = src_base + (size_t)row * DK + (((slot ^ (row & 15)) << 3));
        ushort* l = lds_base + (size_t)(r0 + j * 4) * DK;   // wave-uniform
        __builtin_amdgcn_global_load_lds((gas_t*)g, (las_t*)l, 16, 0, 0);
    }
}

// Kernel 2: fused bf16-MFMA dist^2 + masked max/min in t = sqb - 2*dot domain.
// Block = 4 waves, 128x128 tile; wave = 64x64 quadrant. A and B tiles staged in
// swizzled LDS (global_load_lds dwordx4), frags via ds_read_b128 (2-way banks).
// Grid (N/128, NSPLIT) = 1024 blocks; LDS 68.5 KB -> 2 blocks/CU.
__global__ __launch_bounds__(256, 2) void tile_kernel(
    const ushort* __restrict__ xb, const float* __restrict__ sq,
    const int* __restrict__ lab,
    unsigned* __restrict__ hp_bits, unsigned* __restrict__ hn_bits,
    unsigned* __restrict__ bcnt, float* __restrict__ out, int N)
{
    __shared__ __align__(16) ushort a_s[128 * DK];
    __shared__ __align__(16) ushort b_s[128 * DK];
    __shared__ int   laba_s[128];
    __shared__ float red_hp[128][2];
    __shared__ float red_hn[128][2];
    __shared__ float s_sum[256];
    __shared__ float s_cnt[256];
    __shared__ bool  s_last;

    const int tid  = threadIdx.x;
    const int lane = tid & 63;
    const int wave = tid >> 6;
    const int m16  = lane & 15;
    const int quad = lane >> 4;
    const int rbase = blockIdx.x * 128;
    const int wrow = (wave >> 1) * 64;
    const int wcol = (wave & 1) * 64;

    // Stage A tile once (each wave stages 32 rows).
    stage32(xb + (size_t)rbase * DK, a_s, wave * 32, lane);
    if (tid < 128) laba_s[tid] = lab[rbase + tid];
    __syncthreads();

    int rlab[4][4];
    #pragma unroll
    for (int mt = 0; mt < 4; ++mt)
        #pragma unroll
        for (int r = 0; r < 4; ++r)
            rlab[mt][r] = laba_s[wrow + mt * 16 + quad * 4 + r];

    float runhp[4][4], runhn[4][4];
    #pragma unroll
    for (int mt = 0; mt < 4; ++mt)
        #pragma unroll
        for (int r = 0; r < 4; ++r) { runhp[mt][r] = -BIGF; runhn[mt][r] = BIGF; }

    const int cps = N / NSPLIT;                 // 512
    const int cbegin = blockIdx.y * cps;

    for (int ci = 0; ci < cps; ci += 128) {
        const int cbase = cbegin + ci;

        __syncthreads();            // prev-iter frag reads done before overwrite
        stage32(xb + (size_t)cbase * DK, b_s, wave * 32, lane);

        float sqbv[4]; int lbv[4];
        #pragma unroll
        for (int nt = 0; nt < 4; ++nt) {
            int colg = cbase + wcol + nt * 16 + m16;
            sqbv[nt] = sq[colg];
            lbv[nt]  = lab[colg];
        }
        __syncthreads();            // vmcnt(0) drain -> B tile ready

        f32x4 acc[4][4];
        #pragma unroll
        for (int mt = 0; mt < 4; ++mt)
            #pragma unroll
            for (int nt = 0; nt < 4; ++nt)
                acc[mt][nt] = (f32x4){0.f, 0.f, 0.f, 0.f};

        #pragma unroll
        for (int s = 0; s < 4; ++s) {
            const int cswz = ((s * 4 + quad) ^ m16) << 3;   // swizzled chunk (ushort off)
            bf16x8 afr[4], bfr[4];
            #pragma unroll
            for (int mt = 0; mt < 4; ++mt)
                afr[mt] = *(const bf16x8*)(a_s + (wrow + mt * 16 + m16) * DK + cswz);
            #pragma unroll
            for (int nt = 0; nt < 4; ++nt)
                bfr[nt] = *(const bf16x8*)(b_s + (wcol + nt * 16 + m16) * DK + cswz);
            #pragma unroll
            for (int mt = 0; mt < 4; ++mt)
                #pragma unroll
                for (int nt = 0; nt < 4; ++nt)
                    acc[mt][nt] = __builtin_amdgcn_mfma_f32_16x16x32_bf16(
                        afr[mt], bfr[nt], acc[mt][nt], 0, 0, 0);
        }

        if (cbase == rbase) {
            // diagonal tile (wave-uniform branch): exclude self-pairs from hp
            #pragma unroll
            for (int nt = 0; nt < 4; ++nt) {
                int colg = cbase + wcol + nt * 16 + m16;
                #pragma unroll
                for (int mt = 0; mt < 4; ++mt)
                    #pragma unroll
                    for (int r = 0; r < 4; ++r) {
                        float t = fmaf(-2.0f, acc[mt][nt][r], sqbv[nt]);
                        int rowg = rbase + wrow + mt * 16 + quad * 4 + r;
                        bool same = (rlab[mt][r] == lbv[nt]);
                        bool pos = same && (rowg != colg);
                        runhp[mt][r] = fmaxf(runhp[mt][r], pos ? t : -BIGF);
                        runhn[mt][r] = fminf(runhn[mt][r], same ? BIGF : t);
                    }
            }
        } else {
            #pragma unroll
            for (int nt = 0; nt < 4; ++nt) {
                #pragma unroll
                for (int mt = 0; mt < 4; ++mt)
                    #pragma unroll
                    for (int r = 0; r < 4; ++r) {
                        float t = fmaf(-2.0f, acc[mt][nt][r], sqbv[nt]);
                        bool same = (rlab[mt][r] == lbv[nt]);
                        runhp[mt][r] = fmaxf(runhp[mt][r], same ? t : -BIGF);
                        runhn[mt][r] = fminf(runhn[mt][r], same ? BIGF : t);
                    }
            }
        }
    }

    // reduce across the 16 m16-lanes sharing each row
    #pragma unroll
    for (int mt = 0; mt < 4; ++mt)
        #pragma unroll
        for (int r = 0; r < 4; ++r) {
            #pragma unroll
            for (int o = 8; o > 0; o >>= 1) {
                runhp[mt][r] = fmaxf(runhp[mt][r], __shfl_xor(runhp[mt][r], o, 16));
                runhn[mt][r] = fminf(runhn[mt][r], __shfl_xor(runhn[mt][r], o, 16));
            }
        }

    if (m16 == 0) {
        #pragma unroll
        for (int mt = 0; mt < 4; ++mt)
            #pragma unroll
            for (int r = 0; r < 4; ++r) {
                int rowl = wrow + mt * 16 + quad * 4 + r;
                red_hp[rowl][wave & 1] = runhp[mt][r];
                red_hn[rowl][wave & 1] = runhn[mt][r];
            }
    }
    __syncthreads();
    if (tid < 128) {
        float thp = fmaxf(red_hp[tid][0], red_hp[tid][1]);
        float thn = fminf(red_hn[tid][0], red_hn[tid][1]);
        float sqa = sq[rbase + tid];
        atomicMax(&hp_bits[rbase + tid], encf(sqa + thp));
        atomicMax(&hn_bits[rbase + tid], ~encf(sqa + thn));
    }

    // ---- last block does the finalize ----
    __syncthreads();
    __threadfence();
    if (tid == 0) {
        unsigned tot = gridDim.x * gridDim.y;
        unsigned o = atomicAdd(bcnt, 1u);
        s_last = (o == tot - 1);
    }
    __syncthreads();
    if (!s_last) return;

    float lsum = 0.0f, lcnt = 0.0f;
    for (int base = 0; base < N; base += 256 * 8) {
        unsigned kp[8], kn[8];
        #pragma unroll
        for (int j = 0; j < 8; ++j) {
            int r = base + j * 256 + tid;
            kp[j] = (r < N) ? __hip_atomic_load(&hp_bits[r], __ATOMIC_RELAXED,
                                                __HIP_MEMORY_SCOPE_AGENT) : 0u;
            kn[j] = (r < N) ? __hip_atomic_load(&hn_bits[r], __ATOMIC_RELAXED,
                                                __HIP_MEMORY_SCOPE_AGENT) : 0u;
        }
        #pragma unroll
        for (int j = 0; j < 8; ++j) {
            int r = base + j * 256 + tid;
            if (r >= N) continue;
            float hpv = decf(kp[j]);
            float hnv = decf(~kn[j]);
            if (hpv > -0.5f * BIGF && hnv < 0.5f * BIGF) {
                float dp = sqrtf(fmaxf(hpv, 0.0f));
                float dn = sqrtf(fmaxf(hnv, 0.0f));
                lsum += fmaxf(dp - dn + MARGIN, 0.0f);
                lcnt += 1.0f;
            }
        }
    }
    s_sum[tid] = lsum; s_cnt[tid] = lcnt;
    __syncthreads();
    for (int o = 128; o > 0; o >>= 1) {
        if (tid < o) { s_sum[tid] += s_sum[tid + o]; s_cnt[tid] += s_cnt[tid + o]; }
        __syncthreads();
    }
    if (tid == 0) out[0] = (s_cnt[0] > 0.0f) ? s_sum[0] / s_cnt[0] : 0.0f;
}

extern "C" void kernel_launch(void* const* d_in, const int* in_sizes, int n_in,
                              void* d_out, int out_size, void* d_ws, size_t ws_size,
                              hipStream_t stream) {
    const float* x = (const float*)d_in[0];
    const int* lab = (const int*)d_in[1];
    float* out = (float*)d_out;
    const int N = in_sizes[1];          // 8192

    unsigned* ws = (unsigned*)d_ws;
    unsigned* hp_bits = ws + WS_HP;
    unsigned* hn_bits = ws + WS_HN;
    unsigned* bcnt    = ws + WS_BCNT;
    float* sq  = (float*)(ws + WS_SQ);
    ushort* xb = (ushort*)(ws + WS_XB);

    prep_kernel<<<N / 4, 256, 0, stream>>>(x, xb, sq, hp_bits, hn_bits, bcnt, N);
    dim3 grid(N / 128, NSPLIT);
    tile_kernel<<<grid, 256, 0, stream>>>(xb, sq, lab, hp_bits, hn_bits, bcnt, out, N);
}

// Round 8
// 150.458 us; speedup vs baseline: 1.2647x; 1.0104x over previous
//
#include <hip/hip_runtime.h>
#include <hip/hip_bf16.h>

#define NSPLIT 8
#define BIGF 1e30f
#define MARGIN 0.3f
#define DK 128
#define LDA 136   // padded LDS stride (bf16 elems) — R2-verified conflict-free

typedef __attribute__((ext_vector_type(8))) short bf16x8;
typedef __attribute__((ext_vector_type(4))) float f32x4;

// ws word offsets: HP[8192] | HN[8192] | BCNT[1]  (zeroed by hipMemsetAsync)
#define WS_HP   0
#define WS_HN   8192
#define WS_BCNT 16384

// Order-preserving float->uint key; +/-BIGF sentinels survive the atomic-max
// merge and encode validity exactly. Init 0 < every real key.
__device__ __forceinline__ unsigned encf(float f) {
    unsigned u = __float_as_uint(f);
    return (u & 0x80000000u) ? ~u : (u | 0x80000000u);
}
__device__ __forceinline__ float decf(unsigned k) {
    return (k & 0x80000000u) ? __uint_as_float(k & 0x7FFFFFFFu)
                             : __uint_as_float(~k);
}

__device__ __forceinline__ bf16x8 cvt8(f32x4 f0, f32x4 f1) {
    union { bf16x8 v; ushort u[8]; } r;
    float f[8] = {f0.x, f0.y, f0.z, f0.w, f1.x, f1.y, f1.z, f1.w};
    #pragma unroll
    for (int k = 0; k < 8; ++k) {
        __hip_bfloat16 b = __float2bfloat16(f[k]);
        r.u[k] = *(ushort*)&b;
    }
    return r.v;
}

// Wave stages 32 rows of X (f32, global, coalesced) into padded bf16 LDS and
// computes exact fp32 row squared-norms (per-lane fma chain + 16-lane shuffle
// tree — same code path everywhere => bitwise-consistent sq).
__device__ __forceinline__ void stage_cast32(const float* __restrict__ x, int gbase,
                                             ushort* lds, float* sq_lds,
                                             int r0, int lane) {
    const int rsub = lane >> 4;          // 0..3
    const int slot = lane & 15;          // 0..15
    #pragma unroll
    for (int j = 0; j < 8; ++j) {
        int row = r0 + j * 4 + rsub;     // local row in 128-tile
        const f32x4* src = (const f32x4*)(x + (size_t)(gbase + row) * DK + slot * 8);
        f32x4 f0 = src[0];
        f32x4 f1 = src[1];
        *(bf16x8*)(lds + row * LDA + slot * 8) = cvt8(f0, f1);
        float p = f0.x * f0.x;
        p = fmaf(f0.y, f0.y, p);
        p = fmaf(f0.z, f0.z, p);
        p = fmaf(f0.w, f0.w, p);
        p = fmaf(f1.x, f1.x, p);
        p = fmaf(f1.y, f1.y, p);
        p = fmaf(f1.z, f1.z, p);
        p = fmaf(f1.w, f1.w, p);
        #pragma unroll
        for (int o = 1; o < 16; o <<= 1) p += __shfl_xor(p, o, 16);
        if (slot == 0) sq_lds[row] = p;
    }
}

// Single fused kernel: cast+sq in-block, bf16-MFMA dist^2, masked max/min in
// t = sqb - 2*dot domain, atomic key merge, last-block finalize.
// Block = 4 waves, 128x128 tile; wave = 64x64 quadrant. Grid (N/128, NSPLIT)
// = 512 blocks; LDS ~75.8 KB -> 2 blocks/CU co-resident.
__global__ __launch_bounds__(256, 2) void fused_kernel(
    const float* __restrict__ x, const int* __restrict__ lab,
    unsigned* __restrict__ hp_bits, unsigned* __restrict__ hn_bits,
    unsigned* __restrict__ bcnt, float* __restrict__ out, int N)
{
    __shared__ __align__(16) ushort a_s[128 * LDA];
    __shared__ __align__(16) ushort b_s[128 * LDA];
    __shared__ float sqa_s[128];
    __shared__ float sqb_s[128];
    __shared__ int   laba_s[128];
    __shared__ int   labb_s[128];
    __shared__ float red_hp[128][2];
    __shared__ float red_hn[128][2];
    __shared__ float s_sum[256];
    __shared__ float s_cnt[256];
    __shared__ bool  s_last;

    const int tid  = threadIdx.x;
    const int lane = tid & 63;
    const int wave = tid >> 6;
    const int m16  = lane & 15;
    const int quad = lane >> 4;
    const int rbase = blockIdx.x * 128;
    const int wrow = (wave >> 1) * 64;
    const int wcol = (wave & 1) * 64;

    // Stage + cast A tile once; exact sq of A rows into sqa_s.
    stage_cast32(x, rbase, a_s, sqa_s, wave * 32, lane);
    if (tid < 128) laba_s[tid] = lab[rbase + tid];
    __syncthreads();

    int rlab[4][4];
    #pragma unroll
    for (int mt = 0; mt < 4; ++mt)
        #pragma unroll
        for (int r = 0; r < 4; ++r)
            rlab[mt][r] = laba_s[wrow + mt * 16 + quad * 4 + r];

    float runhp[4][4], runhn[4][4];
    #pragma unroll
    for (int mt = 0; mt < 4; ++mt)
        #pragma unroll
        for (int r = 0; r < 4; ++r) { runhp[mt][r] = -BIGF; runhn[mt][r] = BIGF; }

    const int cps = N / NSPLIT;                 // 1024
    const int cbegin = blockIdx.y * cps;

    for (int ci = 0; ci < cps; ci += 128) {
        const int cbase = cbegin + ci;

        __syncthreads();            // prev-iter frag reads of b_s done
        stage_cast32(x, cbase, b_s, sqb_s, wave * 32, lane);
        if (tid < 128) labb_s[tid] = lab[cbase + tid];
        __syncthreads();            // b_s / sqb_s / labb_s ready

        float sqbv[4]; int lbv[4];
        #pragma unroll
        for (int nt = 0; nt < 4; ++nt) {
            int c = wcol + nt * 16 + m16;
            sqbv[nt] = sqb_s[c];
            lbv[nt]  = labb_s[c];
        }

        f32x4 acc[4][4];
        #pragma unroll
        for (int mt = 0; mt < 4; ++mt)
            #pragma unroll
            for (int nt = 0; nt < 4; ++nt)
                acc[mt][nt] = (f32x4){0.f, 0.f, 0.f, 0.f};

        #pragma unroll
        for (int s = 0; s < 4; ++s) {
            bf16x8 afr[4], bfr[4];
            #pragma unroll
            for (int mt = 0; mt < 4; ++mt)
                afr[mt] = *(const bf16x8*)(a_s + (wrow + mt * 16 + m16) * LDA
                                           + s * 32 + quad * 8);
            #pragma unroll
            for (int nt = 0; nt < 4; ++nt)
                bfr[nt] = *(const bf16x8*)(b_s + (wcol + nt * 16 + m16) * LDA
                                           + s * 32 + quad * 8);
            #pragma unroll
            for (int mt = 0; mt < 4; ++mt)
                #pragma unroll
                for (int nt = 0; nt < 4; ++nt)
                    acc[mt][nt] = __builtin_amdgcn_mfma_f32_16x16x32_bf16(
                        afr[mt], bfr[nt], acc[mt][nt], 0, 0, 0);
        }

        if (cbase == rbase) {
            // diagonal tile (wave-uniform branch): exclude self-pairs from hp
            #pragma unroll
            for (int nt = 0; nt < 4; ++nt) {
                int colg = cbase + wcol + nt * 16 + m16;
                #pragma unroll
                for (int mt = 0; mt < 4; ++mt)
                    #pragma unroll
                    for (int r = 0; r < 4; ++r) {
                        float t = fmaf(-2.0f, acc[mt][nt][r], sqbv[nt]);
                        int rowg = rbase + wrow + mt * 16 + quad * 4 + r;
                        bool same = (rlab[mt][r] == lbv[nt]);
                        bool pos = same && (rowg != colg);
                        runhp[mt][r] = fmaxf(runhp[mt][r], pos ? t : -BIGF);
                        runhn[mt][r] = fminf(runhn[mt][r], same ? BIGF : t);
                    }
            }
        } else {
            #pragma unroll
            for (int nt = 0; nt < 4; ++nt) {
                #pragma unroll
                for (int mt = 0; mt < 4; ++mt)
                    #pragma unroll
                    for (int r = 0; r < 4; ++r) {
                        float t = fmaf(-2.0f, acc[mt][nt][r], sqbv[nt]);
                        bool same = (rlab[mt][r] == lbv[nt]);
                        runhp[mt][r] = fmaxf(runhp[mt][r], same ? t : -BIGF);
                        runhn[mt][r] = fminf(runhn[mt][r], same ? BIGF : t);
                    }
            }
        }
    }

    // reduce across the 16 m16-lanes sharing each row
    #pragma unroll
    for (int mt = 0; mt < 4; ++mt)
        #pragma unroll
        for (int r = 0; r < 4; ++r) {
            #pragma unroll
            for (int o = 8; o > 0; o >>= 1) {
                runhp[mt][r] = fmaxf(runhp[mt][r], __shfl_xor(runhp[mt][r], o, 16));
                runhn[mt][r] = fminf(runhn[mt][r], __shfl_xor(runhn[mt][r], o, 16));
            }
        }

    if (m16 == 0) {
        #pragma unroll
        for (int mt = 0; mt < 4; ++mt)
            #pragma unroll
            for (int r = 0; r < 4; ++r) {
                int rowl = wrow + mt * 16 + quad * 4 + r;
                red_hp[rowl][wave & 1] = runhp[mt][r];
                red_hn[rowl][wave & 1] = runhn[mt][r];
            }
    }
    __syncthreads();
    if (tid < 128) {
        float thp = fmaxf(red_hp[tid][0], red_hp[tid][1]);
        float thn = fminf(red_hn[tid][0], red_hn[tid][1]);
        float sqa = sqa_s[tid];
        atomicMax(&hp_bits[rbase + tid], encf(sqa + thp));
        atomicMax(&hn_bits[rbase + tid], ~encf(sqa + thn));
    }

    // ---- last block does the finalize ----
    __syncthreads();
    __threadfence();
    if (tid == 0) {
        unsigned tot = gridDim.x * gridDim.y;
        unsigned o = atomicAdd(bcnt, 1u);
        s_last = (o == tot - 1);
    }
    __syncthreads();
    if (!s_last) return;

    float lsum = 0.0f, lcnt = 0.0f;
    for (int base = 0; base < N; base += 256 * 8) {
        unsigned kp[8], kn[8];
        #pragma unroll
        for (int j = 0; j < 8; ++j) {
            int r = base + j * 256 + tid;
            kp[j] = (r < N) ? __hip_atomic_load(&hp_bits[r], __ATOMIC_RELAXED,
                                                __HIP_MEMORY_SCOPE_AGENT) : 0u;
            kn[j] = (r < N) ? __hip_atomic_load(&hn_bits[r], __ATOMIC_RELAXED,
                                                __HIP_MEMORY_SCOPE_AGENT) : 0u;
        }
        #pragma unroll
        for (int j = 0; j < 8; ++j) {
            int r = base + j * 256 + tid;
            if (r >= N) continue;
            float hpv = decf(kp[j]);
            float hnv = decf(~kn[j]);
            if (hpv > -0.5f * BIGF && hnv < 0.5f * BIGF) {
                float dp = sqrtf(fmaxf(hpv, 0.0f));
                float dn = sqrtf(fmaxf(hnv, 0.0f));
                lsum += fmaxf(dp - dn + MARGIN, 0.0f);
                lcnt += 1.0f;
            }
        }
    }
    s_sum[tid] = lsum; s_cnt[tid] = lcnt;
    __syncthreads();
    for (int o = 128; o > 0; o >>= 1) {
        if (tid < o) { s_sum[tid] += s_sum[tid + o]; s_cnt[tid] += s_cnt[tid + o]; }
        __syncthreads();
    }
    if (tid == 0) out[0] = (s_cnt[0] > 0.0f) ? s_sum[0] / s_cnt[0] : 0.0f;
}

extern "C" void kernel_launch(void* const* d_in, const int* in_sizes, int n_in,
                              void* d_out, int out_size, void* d_ws, size_t ws_size,
                              hipStream_t stream) {
    const float* x = (const float*)d_in[0];
    const int* lab = (const int*)d_in[1];
    float* out = (float*)d_out;
    const int N = in_sizes[1];          // 8192

    unsigned* ws = (unsigned*)d_ws;
    unsigned* hp_bits = ws + WS_HP;
    unsigned* hn_bits = ws + WS_HN;
    unsigned* bcnt    = ws + WS_BCNT;

    hipMemsetAsync(d_ws, 0, (size_t)(2 * 8192 + 1) * sizeof(unsigned), stream);
    dim3 grid(N / 128, NSPLIT);
    fused_kernel<<<grid, 256, 0, stream>>>(x, lab, hp_bits, hn_bits, bcnt, out, N);
}